// Round 4
// baseline (1295.467 us; speedup 1.0000x reference)
//
#include <hip/hip_runtime.h>
#include <math.h>

#define B_ 128
#define C_ 10
#define R_ 8192
#define I_ 8
#define O_ 16

#define XROW 520               // 64 b * 8 floats + 8 pad (bank rotate)
#define NTILE_R 16             // r per tile
#define NTILES 2               // tiles per block -> 32 r per block

// LDS: x tile 16r x 64b x 8f (padded rows) + W tile 16r x 128f
// ---------------------------------------------------------------------------
// fused_iter: one full routing iteration.
//   mode 0: c_ij = 1/10 (b_ij == 0), phase-2 skipped.
//   mode 1: phase 2 computes D[b,r] = sum_c exp(u.vsum); phase 3 uses
//           c_ij = exp(u.vsum)/D.
// grid: (R_/32, 2 b-halves). block 256 = 4 waves.
//   lane = (bl in 0..31, oh in 0..1); wave w: bw = (w&1)*32+bl, rh = w>>1.
//   Each wave covers 32 b x 8 r (its r-half) x all c, o-half per lane.
// Output: part[slot][c][o][64b] partial s sums (non-atomic).
// ---------------------------------------------------------------------------
__global__ __launch_bounds__(256, 3) void fused_iter(const float* __restrict__ x,
                                                     const float* __restrict__ w,
                                                     const float* __restrict__ vsum,  // [C][B][16]
                                                     float* __restrict__ part,
                                                     int mode) {
    __shared__ float xt[NTILE_R * XROW];   // 33280 B
    __shared__ float wt[NTILE_R * 128];    // 8192 B

    const int bx = blockIdx.x;             // 0..255  (r0 = bx*32)
    const int bh = blockIdx.y;             // 0..1    (b-half)
    const int b0 = bh * 64;
    const int tid = threadIdx.x;
    const int wave = tid >> 6;
    const int lane = tid & 63;
    const int bl = lane & 31;
    const int oh = lane >> 5;
    const int bw = (wave & 1) * 32 + bl;   // 0..63 within half
    const int b = b0 + bw;                 // global batch index
    const int rh = wave >> 1;              // r-half of the tile (0..1)

    float acc[C_][8];
#pragma unroll
    for (int c = 0; c < C_; ++c)
#pragma unroll
        for (int j = 0; j < 8; ++j) acc[c][j] = 0.f;

#pragma unroll 1
    for (int tile = 0; tile < NTILES; ++tile) {
        const int r0t = bx * 32 + tile * NTILE_R;

        // ---- stage x tile: x[b0..b0+64, r0t..r0t+16, :] -> xt[r][bw][8] ----
        __syncthreads();
#pragma unroll
        for (int k = 0; k < 8; ++k) {
            const int f = k * 256 + tid;       // float4 id, 0..2047
            const int b_l = f >> 5;            // 0..63
            const int fr = f & 31;             // r_l*2 + q
            const int r_l = fr >> 1, q = fr & 1;
            const float4 v = ((const float4*)x)[(size_t)(b0 + b_l) * (R_ * 2) + (size_t)(r0t + r_l) * 2 + q];
            float* dst = xt + r_l * XROW + b_l * 8 + q * 4;
            dst[0] = v.x; dst[1] = v.y; dst[2] = v.z; dst[3] = v.w;
        }
        __syncthreads();

        float dacc[8];
#pragma unroll
        for (int k = 0; k < 8; ++k) dacc[k] = 0.f;

        // ================= PHASE 2: denominators (mode 1 only) =============
        if (mode) {
#pragma unroll 1
            for (int c = 0; c < C_; ++c) {
                __syncthreads();
                // stage W[c, r0t..+16, :, :] = 512 float4
                const float4* wsrc = ((const float4*)w) + (size_t)(c * R_ + r0t) * 32;
                ((float4*)wt)[tid] = wsrc[tid];
                ((float4*)wt)[tid + 256] = wsrc[tid + 256];
                __syncthreads();

                // vsum[c][b][oh*8 ..]
                float vs[8];
                {
                    const float4* vp = (const float4*)(vsum + ((size_t)c * B_ + b) * O_ + oh * 8);
                    const float4 v0 = vp[0], v1 = vp[1];
                    vs[0] = v0.x; vs[1] = v0.y; vs[2] = v0.z; vs[3] = v0.w;
                    vs[4] = v1.x; vs[5] = v1.y; vs[6] = v1.z; vs[7] = v1.w;
                }
#pragma unroll
                for (int r8 = 0; r8 < 8; ++r8) {
                    const int rg = rh * 8 + r8;
                    const float* xr = xt + rg * XROW + bw * 8;
                    float u[8];
#pragma unroll
                    for (int j = 0; j < 8; ++j) u[j] = 0.f;
#pragma unroll
                    for (int i = 0; i < 8; ++i) {
                        const float xv = xr[i];
                        const float* wr = wt + rg * 128 + i * 16 + oh * 8;
#pragma unroll
                        for (int j = 0; j < 8; ++j) u[j] += xv * wr[j];
                    }
                    float pd = 0.f;
#pragma unroll
                    for (int j = 0; j < 8; ++j) pd += u[j] * vs[j];
                    const float l = pd + __shfl_xor(pd, 32);
                    dacc[r8] += __expf(l);
                }
            }
#pragma unroll
            for (int k = 0; k < 8; ++k) dacc[k] = 1.0f / dacc[k];   // rcpD
        }

        // ================= PHASE 3: s accumulation =========================
#pragma unroll 1
        for (int c = 0; c < C_; ++c) {
            __syncthreads();
            const float4* wsrc = ((const float4*)w) + (size_t)(c * R_ + r0t) * 32;
            ((float4*)wt)[tid] = wsrc[tid];
            ((float4*)wt)[tid + 256] = wsrc[tid + 256];
            __syncthreads();

            float vs[8];
            if (mode) {
                const float4* vp = (const float4*)(vsum + ((size_t)c * B_ + b) * O_ + oh * 8);
                const float4 v0 = vp[0], v1 = vp[1];
                vs[0] = v0.x; vs[1] = v0.y; vs[2] = v0.z; vs[3] = v0.w;
                vs[4] = v1.x; vs[5] = v1.y; vs[6] = v1.z; vs[7] = v1.w;
            }
#pragma unroll
            for (int r8 = 0; r8 < 8; ++r8) {
                const int rg = rh * 8 + r8;
                const float* xr = xt + rg * XROW + bw * 8;
                float u[8];
#pragma unroll
                for (int j = 0; j < 8; ++j) u[j] = 0.f;
#pragma unroll
                for (int i = 0; i < 8; ++i) {
                    const float xv = xr[i];
                    const float* wr = wt + rg * 128 + i * 16 + oh * 8;
#pragma unroll
                    for (int j = 0; j < 8; ++j) u[j] += xv * wr[j];
                }
                float cij;
                if (mode) {
                    float pd = 0.f;
#pragma unroll
                    for (int j = 0; j < 8; ++j) pd += u[j] * vs[j];
                    const float l = pd + __shfl_xor(pd, 32);
                    cij = __expf(l) * dacc[r8];
                } else {
                    cij = 0.1f;
                }
#pragma unroll
                for (int j = 0; j < 8; ++j) acc[c][j] += cij * u[j];
            }
        }
    }

    // ---- reduce r-half wave pairs (waves 2,3 -> 0,1) via LDS, 2 rounds ----
    float* dump = xt;  // reuse (5120 floats per round)
#pragma unroll 1
    for (int rnd = 0; rnd < 2; ++rnd) {
        const int cc0 = rnd * 5;
        __syncthreads();
        if (wave >= 2) {
            float* d = dump + ((wave - 2) * 64 + lane) * 40;
#pragma unroll
            for (int cc = 0; cc < 5; ++cc)
#pragma unroll
                for (int j = 0; j < 8; ++j) d[cc * 8 + j] = acc[cc0 + cc][j];
        }
        __syncthreads();
        if (wave < 2) {
            const float* d = dump + (wave * 64 + lane) * 40;
#pragma unroll
            for (int cc = 0; cc < 5; ++cc)
#pragma unroll
                for (int j = 0; j < 8; ++j) acc[cc0 + cc][j] += d[cc * 8 + j];
        }
    }

    // ---- waves 0,1 write partials: part[slot][c][o][64] ----
    if (wave < 2) {
        const size_t slot = (size_t)bh * 256 + bx;
#pragma unroll
        for (int c = 0; c < C_; ++c)
#pragma unroll
            for (int j = 0; j < 8; ++j)
                part[((slot * C_ + c) * O_ + oh * 8 + j) * 64 + bw] = acc[c][j];
    }
}

// s_t[c][o][b] = sum over 256 r-blocks of part[(bh*256+bx)][c][o][b&63]
__global__ __launch_bounds__(256) void reduce_pass(const float* __restrict__ part,
                                                   float* __restrict__ s_t) {
    const int t = blockIdx.x * 256 + threadIdx.x;  // 0..20479 = (c*16+o)*128+b
    const int co = t >> 7;        // c*16+o
    const int b = t & 127;
    const int bh = b >> 6, bw = b & 63;
    float sum = 0.f;
#pragma unroll 4
    for (int bx = 0; bx < 256; ++bx) {
        const size_t slot = (size_t)bh * 256 + bx;
        sum += part[(slot * (C_ * O_) + co) * 64 + bw];
    }
    s_t[t] = sum;
}

// squash + vsum update. mode 0: vsum = v; 1: vsum += v; 2: out = v.
__global__ __launch_bounds__(256) void v_pass(const float* __restrict__ s_t,
                                              float* __restrict__ vsum,   // [C][B][16]
                                              float* __restrict__ out,    // [B][C][16]
                                              int mode) {
    const int t = blockIdx.x * 256 + threadIdx.x;  // b*10 + c
    if (t >= B_ * C_) return;
    const int b = t / C_, c = t % C_;
    float sv[16];
    float sq = 0.f;
#pragma unroll
    for (int o = 0; o < 16; ++o) {
        sv[o] = s_t[(c * O_ + o) * B_ + b];
        sq += sv[o] * sv[o];
    }
    const float scale = sq / ((1.0f + sq) * sqrtf(sq + 1e-8f));
    float* vp = vsum + ((size_t)c * B_ + b) * O_;
    if (mode == 0) {
#pragma unroll
        for (int o = 0; o < 16; ++o) vp[o] = scale * sv[o];
    } else if (mode == 1) {
#pragma unroll
        for (int o = 0; o < 16; ++o) vp[o] += scale * sv[o];
    } else {
#pragma unroll
        for (int o = 0; o < 16; ++o) out[(size_t)b * (C_ * O_) + c * O_ + o] = scale * sv[o];
    }
}

extern "C" void kernel_launch(void* const* d_in, const int* in_sizes, int n_in,
                              void* d_out, int out_size, void* d_ws, size_t ws_size,
                              hipStream_t stream) {
    const float* x = (const float*)d_in[0];   // [B,R,8]
    const float* w = (const float*)d_in[1];   // [C,R,8,16]
    float* out = (float*)d_out;               // [B,C,16]

    float* part = (float*)d_ws;                        // 512*10*16*64 = 5.24M floats (21 MB)
    float* s_t  = part + (size_t)512 * C_ * O_ * 64;   // 20480 floats
    float* vsum = s_t + (size_t)C_ * O_ * B_;          // 20480 floats ([C][B][16])

    const dim3 fgrid(R_ / 32, 2);
    const dim3 rgrid(C_ * O_ * B_ / 256);   // 80
    const dim3 vgrid((B_ * C_ + 255) / 256);

    // iteration 0 (uniform c_ij)
    fused_iter<<<fgrid, 256, 0, stream>>>(x, w, vsum, part, 0);
    reduce_pass<<<rgrid, 256, 0, stream>>>(part, s_t);
    v_pass<<<vgrid, 256, 0, stream>>>(s_t, vsum, out, 0);

    // iteration 1
    fused_iter<<<fgrid, 256, 0, stream>>>(x, w, vsum, part, 1);
    reduce_pass<<<rgrid, 256, 0, stream>>>(part, s_t);
    v_pass<<<vgrid, 256, 0, stream>>>(s_t, vsum, out, 1);

    // iteration 2 (final: write out)
    fused_iter<<<fgrid, 256, 0, stream>>>(x, w, vsum, part, 1);
    reduce_pass<<<rgrid, 256, 0, stream>>>(part, s_t);
    v_pass<<<vgrid, 256, 0, stream>>>(s_t, vsum, out, 2);
}

// Round 5
// 299.876 us; speedup vs baseline: 4.3200x; 4.3200x over previous
//
#include <hip/hip_runtime.h>
#include <hip/hip_fp16.h>
#include <math.h>

#define B_ 128
#define C_ 10
#define R_ 8192
#define I_ 8
#define O_ 16

typedef __attribute__((ext_vector_type(8))) short short8;
typedef __attribute__((ext_vector_type(16))) float f32x16;

// x LDS: [8 r][128 b][12 b32] (8 bf16 hi, 8 bf16 lo, 4 pad) ; stride tiles banks per 8-lane octet
#define XRS 12
#define XRROW (128 * XRS)          // per-r stride = 1536 b32
// W LDS: [9 rows][16 o][12 b32] (8 hi, 8 lo, 4 pad); row 8 = zero row
#define WOS 12
#define WRS (16 * WOS)             // 192 b32 per row

__device__ __forceinline__ unsigned int pk_hi(float a, float b) {
    return (__float_as_uint(a) >> 16) | (__float_as_uint(b) & 0xffff0000u);
}
__device__ __forceinline__ float hi_of(float a) {
    return __uint_as_float(__float_as_uint(a) & 0xffff0000u);
}
__device__ __forceinline__ unsigned int pk_h16(float a, float b) {
    return (unsigned int)__half_as_ushort(__float2half(a)) |
           ((unsigned int)__half_as_ushort(__float2half(b)) << 16);
}

// ---------------------------------------------------------------------------
// fused_iter: one routing iteration. grid 1024 (r-tiles of 8), block 256.
// wave covers 32 b (all 4 waves = 128 b). Per (c, r-pair): one 32x32x16 MFMA
// triple (bf16 hi/lo 3-term) computes u[2r x 16o][32b].
// mode 0: cij = 0.1; mode 1: softmax over c with logits u.vsum.
// Output: part[slot=blockIdx.x][c][b][o] fp16 partial s sums.
// ---------------------------------------------------------------------------
__global__ __launch_bounds__(256, 2) void fused_iter(const float* __restrict__ x,
                                                     const float* __restrict__ w,
                                                     const float* __restrict__ vsum,  // [C][B][16]
                                                     __half* __restrict__ part,
                                                     int mode) {
    __shared__ unsigned int xls[8 * XRROW];   // 48 KB
    __shared__ unsigned int wls[9 * WRS];     // 6912 B

    const int tid = threadIdx.x;
    const int wave = tid >> 6;
    const int lane = tid & 63;
    const int n = lane & 31;          // b within wave
    const int g = lane >> 5;          // k-block / o-half selector
    const int rp_m = (lane & 31) >> 4; // r' carried by this lane's A rows? (A-side m>>4)
    const int o_m = lane & 15;        // A-side o (only meaningful pattern-wise)
    const int b = wave * 32 + n;      // global batch 0..127
    const int r0 = blockIdx.x * 8;

    // ---- stage x tile (fp32 -> bf16 hi/lo), once ----
#pragma unroll
    for (int k = 0; k < 8; ++k) {
        const int f = k * 256 + tid;            // 0..2047
        const int bb = f >> 4;
        const int rr = (f >> 1) & 7;
        const int q = f & 1;
        const float4 v = *(const float4*)(x + ((size_t)bb * R_ + r0 + rr) * 8 + q * 4);
        const unsigned int h01 = pk_hi(v.x, v.y), h23 = pk_hi(v.z, v.w);
        const float lx = v.x - hi_of(v.x), ly = v.y - hi_of(v.y);
        const float lz = v.z - hi_of(v.z), lw = v.w - hi_of(v.w);
        const unsigned int l01 = pk_hi(lx, ly), l23 = pk_hi(lz, lw);
        unsigned int* dst = xls + rr * XRROW + bb * XRS + q * 2;
        *(uint2*)(dst) = make_uint2(h01, h23);
        *(uint2*)(dst + 4) = make_uint2(l01, l23);
    }
    // zero row for inactive A lanes
    if (tid < WRS) wls[8 * WRS + tid] = 0u;

    float dacc[8];
#pragma unroll
    for (int j = 0; j < 8; ++j) dacc[j] = 0.f;

    // W row index for A-fragments (zero row if lane inactive)
    const int wrow_act = (g == rp_m);

    // ================= PHASE 2: denominators (mode 1) =================
    if (mode) {
#pragma unroll 1
        for (int c = 0; c < C_; ++c) {
            __syncthreads();
            if (tid < 128) {   // stage W[c, r-tile] -> o-major bf16 hi/lo
                const int r = tid >> 4, o = tid & 15;
                const float* wp = w + ((size_t)(c * R_ + r0 + r) * 8) * 16 + o;
                float f0 = wp[0], f1 = wp[16], f2 = wp[32], f3 = wp[48];
                float f4 = wp[64], f5 = wp[80], f6 = wp[96], f7 = wp[112];
                uint4 h = make_uint4(pk_hi(f0, f1), pk_hi(f2, f3), pk_hi(f4, f5), pk_hi(f6, f7));
                uint4 l = make_uint4(pk_hi(f0 - hi_of(f0), f1 - hi_of(f1)),
                                     pk_hi(f2 - hi_of(f2), f3 - hi_of(f3)),
                                     pk_hi(f4 - hi_of(f4), f5 - hi_of(f5)),
                                     pk_hi(f6 - hi_of(f6), f7 - hi_of(f7)));
                uint4* dst = (uint4*)(wls + r * WRS + o * WOS);
                dst[0] = h; dst[1] = l;
            }
            __syncthreads();

            const float4* vp = (const float4*)(vsum + ((size_t)c * B_ + b) * O_ + 4 * g);
            const float4 va = vp[0];   // o = 4g..4g+3
            const float4 vb = vp[2];   // o = 8+4g..
#pragma unroll
            for (int rp = 0; rp < 4; ++rp) {
                const int wrow = wrow_act ? (2 * rp + g) : 8;
                const short8* wa = (const short8*)(wls + wrow * WRS + o_m * WOS);
                const short8 ah = wa[0], al = wa[1];
                const short8* xp = (const short8*)(xls + (2 * rp + g) * XRROW + b * XRS);
                const short8 xh = xp[0], xl = xp[1];
                f32x16 u;
#pragma unroll
                for (int j = 0; j < 16; ++j) u[j] = 0.f;
                u = __builtin_amdgcn_mfma_f32_32x32x16_bf16(ah, xh, u, 0, 0, 0);
                u = __builtin_amdgcn_mfma_f32_32x32x16_bf16(al, xh, u, 0, 0, 0);
                u = __builtin_amdgcn_mfma_f32_32x32x16_bf16(ah, xl, u, 0, 0, 0);
                float p0 = u[0] * va.x + u[1] * va.y + u[2] * va.z + u[3] * va.w
                         + u[4] * vb.x + u[5] * vb.y + u[6] * vb.z + u[7] * vb.w;
                float p1 = u[8] * va.x + u[9] * va.y + u[10] * va.z + u[11] * va.w
                         + u[12] * vb.x + u[13] * vb.y + u[14] * vb.z + u[15] * vb.w;
                p0 += __shfl_xor(p0, 32);
                p1 += __shfl_xor(p1, 32);
                dacc[2 * rp] += __expf(p0);
                dacc[2 * rp + 1] += __expf(p1);
            }
        }
#pragma unroll
        for (int j = 0; j < 8; ++j) dacc[j] = 1.0f / dacc[j];
    }

    // ================= PHASE 3: s accumulation =================
#pragma unroll 1
    for (int c = 0; c < C_; ++c) {
        __syncthreads();
        if (tid < 128) {
            const int r = tid >> 4, o = tid & 15;
            const float* wp = w + ((size_t)(c * R_ + r0 + r) * 8) * 16 + o;
            float f0 = wp[0], f1 = wp[16], f2 = wp[32], f3 = wp[48];
            float f4 = wp[64], f5 = wp[80], f6 = wp[96], f7 = wp[112];
            uint4 h = make_uint4(pk_hi(f0, f1), pk_hi(f2, f3), pk_hi(f4, f5), pk_hi(f6, f7));
            uint4 l = make_uint4(pk_hi(f0 - hi_of(f0), f1 - hi_of(f1)),
                                 pk_hi(f2 - hi_of(f2), f3 - hi_of(f3)),
                                 pk_hi(f4 - hi_of(f4), f5 - hi_of(f5)),
                                 pk_hi(f6 - hi_of(f6), f7 - hi_of(f7)));
            uint4* dst = (uint4*)(wls + r * WRS + o * WOS);
            dst[0] = h; dst[1] = l;
        }
        __syncthreads();

        float4 va, vb;
        if (mode) {
            const float4* vp = (const float4*)(vsum + ((size_t)c * B_ + b) * O_ + 4 * g);
            va = vp[0]; vb = vp[2];
        }
        f32x16 acc;
#pragma unroll
        for (int j = 0; j < 16; ++j) acc[j] = 0.f;

#pragma unroll
        for (int rp = 0; rp < 4; ++rp) {
            const int wrow = wrow_act ? (2 * rp + g) : 8;
            const short8* wa = (const short8*)(wls + wrow * WRS + o_m * WOS);
            const short8 ah = wa[0], al = wa[1];
            const short8* xp = (const short8*)(xls + (2 * rp + g) * XRROW + b * XRS);
            const short8 xh = xp[0], xl = xp[1];
            f32x16 u;
#pragma unroll
            for (int j = 0; j < 16; ++j) u[j] = 0.f;
            u = __builtin_amdgcn_mfma_f32_32x32x16_bf16(ah, xh, u, 0, 0, 0);
            u = __builtin_amdgcn_mfma_f32_32x32x16_bf16(al, xh, u, 0, 0, 0);
            u = __builtin_amdgcn_mfma_f32_32x32x16_bf16(ah, xl, u, 0, 0, 0);
            float c0, c1;
            if (mode) {
                float p0 = u[0] * va.x + u[1] * va.y + u[2] * va.z + u[3] * va.w
                         + u[4] * vb.x + u[5] * vb.y + u[6] * vb.z + u[7] * vb.w;
                float p1 = u[8] * va.x + u[9] * va.y + u[10] * va.z + u[11] * va.w
                         + u[12] * vb.x + u[13] * vb.y + u[14] * vb.z + u[15] * vb.w;
                p0 += __shfl_xor(p0, 32);
                p1 += __shfl_xor(p1, 32);
                c0 = __expf(p0) * dacc[2 * rp];
                c1 = __expf(p1) * dacc[2 * rp + 1];
            } else {
                c0 = 0.1f; c1 = 0.1f;
            }
#pragma unroll
            for (int j = 0; j < 8; ++j) acc[j] += c0 * u[j];
#pragma unroll
            for (int j = 8; j < 16; ++j) acc[j] += c1 * u[j];
        }

        // fold r' pairs -> s partials for 8 o's, write fp16
        float f0 = acc[0] + acc[8],  f1 = acc[1] + acc[9];
        float f2 = acc[2] + acc[10], f3 = acc[3] + acc[11];
        float f4 = acc[4] + acc[12], f5 = acc[5] + acc[13];
        float f6 = acc[6] + acc[14], f7 = acc[7] + acc[15];
        __half* pp = part + (((size_t)blockIdx.x * C_ + c) * B_ + b) * O_;
        *(uint2*)(pp + 4 * g)     = make_uint2(pk_h16(f0, f1), pk_h16(f2, f3));
        *(uint2*)(pp + 8 + 4 * g) = make_uint2(pk_h16(f4, f5), pk_h16(f6, f7));
    }
}

// s_t[c][b][o] (fp32) += partial sums over 128 slots per block.y
__global__ __launch_bounds__(256) void reduce_pass(const __half* __restrict__ part,
                                                   float* __restrict__ s_t) {
    const int t = blockIdx.x * 256 + threadIdx.x;   // 0..20479 = (c*128+b)*16+o
    const int s0 = blockIdx.y * 128;
    float sum = 0.f;
#pragma unroll 8
    for (int s = 0; s < 128; ++s)
        sum += __half2float(part[(size_t)(s0 + s) * (C_ * B_ * O_) + t]);
    atomicAdd(s_t + t, sum);
}

// squash. mode 0: vsum = v; 1: vsum += v; 2: out = v.
__global__ __launch_bounds__(256) void v_pass(const float* __restrict__ s_t,  // [C][B][16]
                                              float* __restrict__ vsum,       // [C][B][16]
                                              float* __restrict__ out,        // [B][C][16]
                                              int mode) {
    const int t = blockIdx.x * 256 + threadIdx.x;  // b*10 + c
    if (t >= B_ * C_) return;
    const int b = t / C_, c = t % C_;
    float sv[16];
    float sq = 0.f;
#pragma unroll
    for (int o = 0; o < 16; ++o) {
        sv[o] = s_t[((size_t)c * B_ + b) * O_ + o];
        sq += sv[o] * sv[o];
    }
    const float scale = sq / ((1.0f + sq) * sqrtf(sq + 1e-8f));
    float* vp = vsum + ((size_t)c * B_ + b) * O_;
    if (mode == 0) {
#pragma unroll
        for (int o = 0; o < 16; ++o) vp[o] = scale * sv[o];
    } else if (mode == 1) {
#pragma unroll
        for (int o = 0; o < 16; ++o) vp[o] += scale * sv[o];
    } else {
#pragma unroll
        for (int o = 0; o < 16; ++o) out[(size_t)b * (C_ * O_) + c * O_ + o] = scale * sv[o];
    }
}

extern "C" void kernel_launch(void* const* d_in, const int* in_sizes, int n_in,
                              void* d_out, int out_size, void* d_ws, size_t ws_size,
                              hipStream_t stream) {
    const float* x = (const float*)d_in[0];   // [B,R,8]
    const float* w = (const float*)d_in[1];   // [C,R,8,16]
    float* out = (float*)d_out;               // [B,C,16]

    __half* part = (__half*)d_ws;                              // 1024*10*128*16 fp16 = 41.94 MB
    float* s_t  = (float*)(part + (size_t)1024 * C_ * B_ * O_); // 20480 f
    float* vsum = s_t + (size_t)C_ * B_ * O_;                   // 20480 f

    const dim3 fgrid(R_ / 8);           // 1024
    const dim3 rgrid(C_ * B_ * O_ / 256, 8);  // (80, 8)
    const dim3 vgrid((B_ * C_ + 255) / 256);
    const size_t stb = (size_t)C_ * B_ * O_ * sizeof(float);

    // iteration 0 (uniform cij)
    hipMemsetAsync(s_t, 0, stb, stream);
    fused_iter<<<fgrid, 256, 0, stream>>>(x, w, vsum, part, 0);
    reduce_pass<<<rgrid, 256, 0, stream>>>(part, s_t);
    v_pass<<<vgrid, 256, 0, stream>>>(s_t, vsum, out, 0);

    // iteration 1
    hipMemsetAsync(s_t, 0, stb, stream);
    fused_iter<<<fgrid, 256, 0, stream>>>(x, w, vsum, part, 1);
    reduce_pass<<<rgrid, 256, 0, stream>>>(part, s_t);
    v_pass<<<vgrid, 256, 0, stream>>>(s_t, vsum, out, 1);

    // iteration 2 (final)
    hipMemsetAsync(s_t, 0, stb, stream);
    fused_iter<<<fgrid, 256, 0, stream>>>(x, w, vsum, part, 1);
    reduce_pass<<<rgrid, 256, 0, stream>>>(part, s_t);
    v_pass<<<vgrid, 256, 0, stream>>>(s_t, vsum, out, 2);
}

// Round 6
// 288.492 us; speedup vs baseline: 4.4905x; 1.0395x over previous
//
#include <hip/hip_runtime.h>
#include <hip/hip_fp16.h>
#include <math.h>

#define B_ 128
#define C_ 10
#define R_ 8192
#define I_ 8
#define O_ 16

typedef __attribute__((ext_vector_type(8))) _Float16 half8;
typedef __attribute__((ext_vector_type(16))) float f32x16;

#define XROW 512           // uints per x r-row: 128 b * 4
#define WROW 64            // uints per W row: 16 o * 4
#define WZERO 80           // zero-row index (block-diagonal A trick)

__device__ __forceinline__ unsigned pk2(float a, float b) {
    __half2 h = __floats2half2_rn(a, b);
    return *(unsigned*)&h;
}

// ---------------------------------------------------------------------------
// fused_iter: one routing iteration. grid 1024 (r-tiles of 8), block 256.
// All 10 c's W tiles staged once as fp16 (20.3 KB) + x tile fp16 (16 KB).
// Per (c, r-pair): ONE 32x32x16 f16 MFMA computes u[2r x 16o][32b].
//   A[m=(r',o)][k=(r'',i)] = block-diag W (zero-row trick for off-diag lanes)
//   B[k][n=b] = x.  D lane layout (verified m74/m101): col=b, rows per reg.
// mode 0: cij = 0.1; mode 1: phase2 computes D then phase3 softmax-weights.
// Output: part[slot=blockIdx.x][c][b][o] fp16 partial s sums.
// ---------------------------------------------------------------------------
__global__ __launch_bounds__(256, 4) void fused_iter(const float* __restrict__ x,
                                                     const float* __restrict__ w,
                                                     const float* __restrict__ vsum,  // [C][B][16]
                                                     __half* __restrict__ part,
                                                     int mode) {
    __shared__ unsigned xls[8 * XROW];          // 16 KB
    __shared__ unsigned wls[(80 + 1) * WROW];   // 20.25 KB (10c x 8r rows + zero row)

    const int tid = threadIdx.x;
    const int wave = tid >> 6;
    const int lane = tid & 63;
    const int n = lane & 31;
    const int g = lane >> 5;            // k-half / o-half selector
    const int rp_m = (lane & 31) >> 4;  // r' of this lane's A row
    const int o_m = lane & 15;          // o of this lane's A row
    const int b = wave * 32 + n;        // global batch 0..127
    const int r0 = blockIdx.x * 8;

    // ---- stage x tile fp16: xls[r][b][4 b32], once ----
#pragma unroll
    for (int k = 0; k < 8; ++k) {
        const int f = k * 256 + tid;            // 0..2047
        const int bb = f >> 4;                  // 16 lanes share b -> 256B coalesced
        const int rr = (f >> 1) & 7;
        const int q = f & 1;
        const float4 v = *(const float4*)(x + ((size_t)bb * R_ + r0 + rr) * 8 + q * 4);
        *(uint2*)(xls + rr * XROW + bb * 4 + q * 2) = make_uint2(pk2(v.x, v.y), pk2(v.z, v.w));
    }
    // ---- stage W for ALL c fp16: wls[c*8+r][o][4 b32], once ----
#pragma unroll
    for (int k = 0; k < 5; ++k) {
        const int id = k * 256 + tid;           // 0..1279 = (c, r, o)
        const int o = id & 15;
        const int r = (id >> 4) & 7;
        const int c = id >> 7;
        const float* wp = w + ((size_t)(c * R_ + r0 + r) * 8) * 16 + o;
        const float f0 = wp[0],  f1 = wp[16],  f2 = wp[32],  f3 = wp[48];
        const float f4 = wp[64], f5 = wp[80],  f6 = wp[96],  f7 = wp[112];
        *(uint4*)(wls + (c * 8 + r) * WROW + o * 4) =
            make_uint4(pk2(f0, f1), pk2(f2, f3), pk2(f4, f5), pk2(f6, f7));
    }
    if (tid < WROW) wls[WZERO * WROW + tid] = 0u;
    __syncthreads();

    float dacc[8];
#pragma unroll
    for (int j = 0; j < 8; ++j) dacc[j] = 0.f;

    const int act = (g == rp_m);

    // ================= PHASE 2: denominators (mode 1) =================
    if (mode) {
#pragma unroll 1
        for (int c = 0; c < C_; ++c) {
            const float4* vp = (const float4*)(vsum + ((size_t)c * B_ + b) * O_ + 4 * g);
            const float4 va = vp[0];   // o = 4g..4g+3
            const float4 vb = vp[2];   // o = 8+4g..
#pragma unroll
            for (int rp = 0; rp < 4; ++rp) {
                const int wrow = act ? (c * 8 + 2 * rp + g) : WZERO;
                const half8 a  = *(const half8*)(wls + wrow * WROW + o_m * 4);
                const half8 xb = *(const half8*)(xls + (2 * rp + g) * XROW + b * 4);
                f32x16 u;
#pragma unroll
                for (int j = 0; j < 16; ++j) u[j] = 0.f;
                u = __builtin_amdgcn_mfma_f32_32x32x16_f16(a, xb, u, 0, 0, 0);
                float p0 = u[0] * va.x + u[1] * va.y + u[2] * va.z + u[3] * va.w
                         + u[4] * vb.x + u[5] * vb.y + u[6] * vb.z + u[7] * vb.w;
                float p1 = u[8] * va.x + u[9] * va.y + u[10] * va.z + u[11] * va.w
                         + u[12] * vb.x + u[13] * vb.y + u[14] * vb.z + u[15] * vb.w;
                p0 += __shfl_xor(p0, 32);
                p1 += __shfl_xor(p1, 32);
                dacc[2 * rp]     += __expf(p0);
                dacc[2 * rp + 1] += __expf(p1);
            }
        }
#pragma unroll
        for (int j = 0; j < 8; ++j) dacc[j] = 1.0f / dacc[j];
    }

    // ================= PHASE 3: s accumulation =================
#pragma unroll 1
    for (int c = 0; c < C_; ++c) {
        float4 va, vb;
        if (mode) {
            const float4* vp = (const float4*)(vsum + ((size_t)c * B_ + b) * O_ + 4 * g);
            va = vp[0]; vb = vp[2];
        }
        f32x16 acc;
#pragma unroll
        for (int j = 0; j < 16; ++j) acc[j] = 0.f;

#pragma unroll
        for (int rp = 0; rp < 4; ++rp) {
            const int wrow = act ? (c * 8 + 2 * rp + g) : WZERO;
            const half8 a  = *(const half8*)(wls + wrow * WROW + o_m * 4);
            const half8 xb = *(const half8*)(xls + (2 * rp + g) * XROW + b * 4);
            f32x16 u;
#pragma unroll
            for (int j = 0; j < 16; ++j) u[j] = 0.f;
            u = __builtin_amdgcn_mfma_f32_32x32x16_f16(a, xb, u, 0, 0, 0);
            float c0, c1;
            if (mode) {
                float p0 = u[0] * va.x + u[1] * va.y + u[2] * va.z + u[3] * va.w
                         + u[4] * vb.x + u[5] * vb.y + u[6] * vb.z + u[7] * vb.w;
                float p1 = u[8] * va.x + u[9] * va.y + u[10] * va.z + u[11] * va.w
                         + u[12] * vb.x + u[13] * vb.y + u[14] * vb.z + u[15] * vb.w;
                p0 += __shfl_xor(p0, 32);
                p1 += __shfl_xor(p1, 32);
                c0 = __expf(p0) * dacc[2 * rp];
                c1 = __expf(p1) * dacc[2 * rp + 1];
            } else {
                c0 = 0.1f; c1 = 0.1f;
            }
#pragma unroll
            for (int j = 0; j < 8; ++j)  acc[j] += c0 * u[j];
#pragma unroll
            for (int j = 8; j < 16; ++j) acc[j] += c1 * u[j];
        }

        // fold r' pairs -> 8 o-partials, write fp16 (waves own disjoint b)
        const float f0 = acc[0] + acc[8],  f1 = acc[1] + acc[9];
        const float f2 = acc[2] + acc[10], f3 = acc[3] + acc[11];
        const float f4 = acc[4] + acc[12], f5 = acc[5] + acc[13];
        const float f6 = acc[6] + acc[14], f7 = acc[7] + acc[15];
        __half* pp = part + (((size_t)blockIdx.x * C_ + c) * B_ + b) * O_;
        *(uint2*)(pp + 4 * g)     = make_uint2(pk2(f0, f1), pk2(f2, f3));
        *(uint2*)(pp + 8 + 4 * g) = make_uint2(pk2(f4, f5), pk2(f6, f7));
    }
}

// ---------------------------------------------------------------------------
// finish_pass: reduce 1024 slot-partials + squash + vsum/out update, fused.
// grid 80 x 256: t = (c*128+b)*16+o. o spans 16 consecutive lanes -> shfl.
// mode 0: vsum = v; 1: vsum += v; 2: out = v.
// ---------------------------------------------------------------------------
__global__ __launch_bounds__(256) void finish_pass(const __half* __restrict__ part,
                                                   float* __restrict__ vsum,   // [C][B][16]
                                                   float* __restrict__ out,    // [B][C][16]
                                                   int mode) {
    const int t = blockIdx.x * 256 + threadIdx.x;
    float sum = 0.f;
    const __half* p = part + t;
#pragma unroll 16
    for (int s = 0; s < 1024; ++s)
        sum += __half2float(p[(size_t)s * (C_ * B_ * O_)]);

    float sq = sum * sum;
    sq += __shfl_xor(sq, 1);
    sq += __shfl_xor(sq, 2);
    sq += __shfl_xor(sq, 4);
    sq += __shfl_xor(sq, 8);
    const float scale = sq / ((1.0f + sq) * sqrtf(sq + 1e-8f));
    const float v = scale * sum;

    if (mode == 0) {
        vsum[t] = v;
    } else if (mode == 1) {
        vsum[t] += v;
    } else {
        const int o = t & 15, b = (t >> 4) & 127, c = t >> 11;
        out[((size_t)b * C_ + c) * O_ + o] = v;
    }
}

extern "C" void kernel_launch(void* const* d_in, const int* in_sizes, int n_in,
                              void* d_out, int out_size, void* d_ws, size_t ws_size,
                              hipStream_t stream) {
    const float* x = (const float*)d_in[0];   // [B,R,8]
    const float* w = (const float*)d_in[1];   // [C,R,8,16]
    float* out = (float*)d_out;               // [B,C,16]

    __half* part = (__half*)d_ws;                               // 1024*20480 fp16 = 41.9 MB
    float* vsum = (float*)(part + (size_t)1024 * C_ * B_ * O_); // 20480 f  ([C][B][16])

    const dim3 fgrid(R_ / 8);                 // 1024
    const dim3 ggrid(C_ * B_ * O_ / 256);     // 80

    // iteration 0 (uniform cij; vsum not read)
    fused_iter<<<fgrid, 256, 0, stream>>>(x, w, vsum, part, 0);
    finish_pass<<<ggrid, 256, 0, stream>>>(part, vsum, out, 0);

    // iteration 1
    fused_iter<<<fgrid, 256, 0, stream>>>(x, w, vsum, part, 1);
    finish_pass<<<ggrid, 256, 0, stream>>>(part, vsum, out, 1);

    // iteration 2 (final: write out)
    fused_iter<<<fgrid, 256, 0, stream>>>(x, w, vsum, part, 1);
    finish_pass<<<ggrid, 256, 0, stream>>>(part, vsum, out, 2);
}

// Round 7
// 228.264 us; speedup vs baseline: 5.6753x; 1.2639x over previous
//
#include <hip/hip_runtime.h>
#include <hip/hip_fp16.h>
#include <math.h>

#define B_ 128
#define C_ 10
#define R_ 8192
#define I_ 8
#define O_ 16

typedef __attribute__((ext_vector_type(8))) _Float16 half8;
typedef __attribute__((ext_vector_type(16))) float f32x16;

#define XROW 512           // uints per x r-row: 128 b * 4
#define WROW 64            // uints per W row: 16 o * 4
#define WZERO 80           // zero-row index (block-diagonal A trick)
#define SBO (C_ * B_ * O_) // 20480

__device__ __forceinline__ unsigned pk2(float a, float b) {
    __half2 h = __floats2half2_rn(a, b);
    return *(unsigned*)&h;
}

// ---------------------------------------------------------------------------
// fused_iter: one routing iteration. grid 1024 (r-tiles of 8), block 256.
// All 10 c's W tiles staged once as fp16 (20.3 KB) + x tile fp16 (16 KB).
// Per (c, r-pair): ONE 32x32x16 f16 MFMA computes u[2r x 16o][32b].
//   A[m=(r',o)][k=(r'',i)] = block-diag W (broadcast-zero for off-diag lanes)
//   B[k][n=b] = x.  D lane layout (verified m74/m101): col=b.
// mode 0: cij = 0.1; mode 1: phase2 computes D then phase3 softmax-weights.
// Output: part[slot=blockIdx.x][c][b][o] fp16 partial s sums.
// ---------------------------------------------------------------------------
__global__ __launch_bounds__(256, 4) void fused_iter(const float* __restrict__ x,
                                                     const float* __restrict__ w,
                                                     const float* __restrict__ vsum,  // [C][B][16]
                                                     __half* __restrict__ part,
                                                     int mode) {
    __shared__ unsigned xls[8 * XROW];          // 16 KB
    __shared__ unsigned wls[(80 + 1) * WROW];   // 20.25 KB

    const int tid = threadIdx.x;
    const int wave = tid >> 6;
    const int lane = tid & 63;
    const int n = lane & 31;
    const int g = lane >> 5;            // k-half / o-half selector
    const int rp_m = (lane & 31) >> 4;  // r' of this lane's A row
    const int o_m = lane & 15;          // o of this lane's A row
    const int b = wave * 32 + n;        // global batch 0..127
    const int r0 = blockIdx.x * 8;

    // ---- stage x tile fp16: xls[r][b][4 b32], once ----
#pragma unroll
    for (int k = 0; k < 8; ++k) {
        const int f = k * 256 + tid;            // 0..2047
        const int bb = f >> 4;
        const int rr = (f >> 1) & 7;
        const int q = f & 1;
        const float4 v = *(const float4*)(x + ((size_t)bb * R_ + r0 + rr) * 8 + q * 4);
        *(uint2*)(xls + rr * XROW + bb * 4 + q * 2) = make_uint2(pk2(v.x, v.y), pk2(v.z, v.w));
    }
    // ---- stage W for ALL c fp16: wls[c*8+r][o][4 b32], once ----
#pragma unroll
    for (int k = 0; k < 5; ++k) {
        const int id = k * 256 + tid;           // 0..1279 = (c, r, o)
        const int o = id & 15;
        const int r = (id >> 4) & 7;
        const int c = id >> 7;
        const float* wp = w + ((size_t)(c * R_ + r0 + r) * 8) * 16 + o;
        const float f0 = wp[0],  f1 = wp[16],  f2 = wp[32],  f3 = wp[48];
        const float f4 = wp[64], f5 = wp[80],  f6 = wp[96],  f7 = wp[112];
        *(uint4*)(wls + (c * 8 + r) * WROW + o * 4) =
            make_uint4(pk2(f0, f1), pk2(f2, f3), pk2(f4, f5), pk2(f6, f7));
    }
    if (tid < WROW) wls[WZERO * WROW + tid] = 0u;
    __syncthreads();

    float dacc[8];
#pragma unroll
    for (int j = 0; j < 8; ++j) dacc[j] = 0.f;

    const int act = (g == rp_m);

    // ================= PHASE 2: denominators (mode 1) =================
    if (mode) {
#pragma unroll 1
        for (int c = 0; c < C_; ++c) {
            const float4* vp = (const float4*)(vsum + ((size_t)c * B_ + b) * O_ + 4 * g);
            const float4 va = vp[0];   // o = 4g..4g+3
            const float4 vb = vp[2];   // o = 8+4g..
#pragma unroll
            for (int rp = 0; rp < 4; ++rp) {
                // broadcast-zero: inactive lanes read the SAME 16B slot (no conflict)
                const int woff = act ? ((c * 8 + 2 * rp + g) * WROW + o_m * 4)
                                     : (WZERO * WROW);
                const half8 a  = *(const half8*)(wls + woff);
                const half8 xb = *(const half8*)(xls + (2 * rp + g) * XROW + b * 4);
                f32x16 u;
#pragma unroll
                for (int j = 0; j < 16; ++j) u[j] = 0.f;
                u = __builtin_amdgcn_mfma_f32_32x32x16_f16(a, xb, u, 0, 0, 0);
                float p0 = u[0] * va.x + u[1] * va.y + u[2] * va.z + u[3] * va.w
                         + u[4] * vb.x + u[5] * vb.y + u[6] * vb.z + u[7] * vb.w;
                float p1 = u[8] * va.x + u[9] * va.y + u[10] * va.z + u[11] * va.w
                         + u[12] * vb.x + u[13] * vb.y + u[14] * vb.z + u[15] * vb.w;
                p0 += __shfl_xor(p0, 32);
                p1 += __shfl_xor(p1, 32);
                dacc[2 * rp]     += __expf(p0);
                dacc[2 * rp + 1] += __expf(p1);
            }
        }
#pragma unroll
        for (int j = 0; j < 8; ++j) dacc[j] = 1.0f / dacc[j];
    }

    // ================= PHASE 3: s accumulation =================
#pragma unroll 1
    for (int c = 0; c < C_; ++c) {
        float4 va, vb;
        if (mode) {
            const float4* vp = (const float4*)(vsum + ((size_t)c * B_ + b) * O_ + 4 * g);
            va = vp[0]; vb = vp[2];
        }
        f32x16 acc;
#pragma unroll
        for (int j = 0; j < 16; ++j) acc[j] = 0.f;

#pragma unroll
        for (int rp = 0; rp < 4; ++rp) {
            const int woff = act ? ((c * 8 + 2 * rp + g) * WROW + o_m * 4)
                                 : (WZERO * WROW);
            const half8 a  = *(const half8*)(wls + woff);
            const half8 xb = *(const half8*)(xls + (2 * rp + g) * XROW + b * 4);
            f32x16 u;
#pragma unroll
            for (int j = 0; j < 16; ++j) u[j] = 0.f;
            u = __builtin_amdgcn_mfma_f32_32x32x16_f16(a, xb, u, 0, 0, 0);
            float c0, c1;
            if (mode) {
                float p0 = u[0] * va.x + u[1] * va.y + u[2] * va.z + u[3] * va.w
                         + u[4] * vb.x + u[5] * vb.y + u[6] * vb.z + u[7] * vb.w;
                float p1 = u[8] * va.x + u[9] * va.y + u[10] * va.z + u[11] * va.w
                         + u[12] * vb.x + u[13] * vb.y + u[14] * vb.z + u[15] * vb.w;
                p0 += __shfl_xor(p0, 32);
                p1 += __shfl_xor(p1, 32);
                c0 = __expf(p0) * dacc[2 * rp];
                c1 = __expf(p1) * dacc[2 * rp + 1];
            } else {
                c0 = 0.1f; c1 = 0.1f;
            }
#pragma unroll
            for (int j = 0; j < 8; ++j)  acc[j] += c0 * u[j];
#pragma unroll
            for (int j = 8; j < 16; ++j) acc[j] += c1 * u[j];
        }

        const float f0 = acc[0] + acc[8],  f1 = acc[1] + acc[9];
        const float f2 = acc[2] + acc[10], f3 = acc[3] + acc[11];
        const float f4 = acc[4] + acc[12], f5 = acc[5] + acc[13];
        const float f6 = acc[6] + acc[14], f7 = acc[7] + acc[15];
        __half* pp = part + (((size_t)blockIdx.x * C_ + c) * B_ + b) * O_;
        *(uint2*)(pp + 4 * g)     = make_uint2(pk2(f0, f1), pk2(f2, f3));
        *(uint2*)(pp + 8 + 4 * g) = make_uint2(pk2(f4, f5), pk2(f6, f7));
    }
}

// ---------------------------------------------------------------------------
// reduce1: part2[by][t] = sum of 64 slot-partials. grid (80,16) = 1280 blocks.
// ---------------------------------------------------------------------------
__global__ __launch_bounds__(256) void reduce1(const __half* __restrict__ part,
                                               float* __restrict__ part2) {
    const int t = blockIdx.x * 256 + threadIdx.x;
    const int s0 = blockIdx.y * 64;
    const __half* p = part + (size_t)s0 * SBO + t;
    float sum = 0.f;
#pragma unroll 8
    for (int s = 0; s < 64; ++s)
        sum += __half2float(p[(size_t)s * SBO]);
    part2[(size_t)blockIdx.y * SBO + t] = sum;
}

// ---------------------------------------------------------------------------
// finish_pass: sum 16 fp32 partials + squash. grid 80.
// t = (c*128+b)*16+o; o spans 16 consecutive lanes -> shfl reduce for ||s||^2.
// mode 0: vsum = v; 1: vsum += v; 2: out = v.
// ---------------------------------------------------------------------------
__global__ __launch_bounds__(256) void finish_pass(const float* __restrict__ part2,
                                                   float* __restrict__ vsum,   // [C][B][16]
                                                   float* __restrict__ out,    // [B][C][16]
                                                   int mode) {
    const int t = blockIdx.x * 256 + threadIdx.x;
    float sum = 0.f;
#pragma unroll
    for (int s = 0; s < 16; ++s)
        sum += part2[(size_t)s * SBO + t];

    float sq = sum * sum;
    sq += __shfl_xor(sq, 1);
    sq += __shfl_xor(sq, 2);
    sq += __shfl_xor(sq, 4);
    sq += __shfl_xor(sq, 8);
    const float scale = sq / ((1.0f + sq) * sqrtf(sq + 1e-8f));
    const float v = scale * sum;

    if (mode == 0) {
        vsum[t] = v;
    } else if (mode == 1) {
        vsum[t] += v;
    } else {
        const int o = t & 15, b = (t >> 4) & 127, c = t >> 11;
        out[((size_t)b * C_ + c) * O_ + o] = v;
    }
}

extern "C" void kernel_launch(void* const* d_in, const int* in_sizes, int n_in,
                              void* d_out, int out_size, void* d_ws, size_t ws_size,
                              hipStream_t stream) {
    const float* x = (const float*)d_in[0];   // [B,R,8]
    const float* w = (const float*)d_in[1];   // [C,R,8,16]
    float* out = (float*)d_out;               // [B,C,16]

    __half* part = (__half*)d_ws;                         // 1024*20480 fp16 = 41.9 MB
    float* part2 = (float*)(part + (size_t)1024 * SBO);   // 16*20480 fp32 = 1.3 MB
    float* vsum  = part2 + (size_t)16 * SBO;              // 20480 f ([C][B][16])

    const dim3 fgrid(R_ / 8);        // 1024
    const dim3 rgrid(80, 16);        // 1280 blocks
    const dim3 ggrid(80);

    // iteration 0 (uniform cij; vsum not read)
    fused_iter<<<fgrid, 256, 0, stream>>>(x, w, vsum, part, 0);
    reduce1<<<rgrid, 256, 0, stream>>>(part, part2);
    finish_pass<<<ggrid, 256, 0, stream>>>(part2, vsum, out, 0);

    // iteration 1
    fused_iter<<<fgrid, 256, 0, stream>>>(x, w, vsum, part, 1);
    reduce1<<<rgrid, 256, 0, stream>>>(part, part2);
    finish_pass<<<ggrid, 256, 0, stream>>>(part2, vsum, out, 1);

    // iteration 2 (final: write out)
    fused_iter<<<fgrid, 256, 0, stream>>>(x, w, vsum, part, 1);
    reduce1<<<rgrid, 256, 0, stream>>>(part, part2);
    finish_pass<<<ggrid, 256, 0, stream>>>(part2, vsum, out, 2);
}